// Round 3
// baseline (707.124 us; speedup 1.0000x reference)
//
#include <hip/hip_runtime.h>
#include <hip/hip_bf16.h>
#include <stdint.h>

#define LROW 25600
#define NCH 256
#define LN_EPS 1e-5f

typedef float f32x4 __attribute__((ext_vector_type(4)));
typedef __bf16 bf16x8 __attribute__((ext_vector_type(8)));

__device__ __forceinline__ bf16x8 cvt8(f32x4 a, f32x4 b) {
  bf16x8 r;
  r[0] = (__bf16)a[0]; r[1] = (__bf16)a[1]; r[2] = (__bf16)a[2]; r[3] = (__bf16)a[3];
  r[4] = (__bf16)b[0]; r[5] = (__bf16)b[1]; r[6] = (__bf16)b[2]; r[7] = (__bf16)b[3];
  return r;
}

// raw barrier: drains LDS ops only, leaves prefetched global loads in flight
__device__ __forceinline__ void wg_bar() {
  asm volatile("s_waitcnt lgkmcnt(0)\n\ts_barrier" ::: "memory");
}

// ---------------------------------------------------------------------------
// Kernel A v3: per-batch Grams  G = Xq Xk^T, Gkk = Xk Xk^T  (+ row sums).
// 256 wgs = 8 b x (21 G + 11 Gkk slices), XCD-remapped so G/Gkk slices with
// overlapping k-ranges of the same batch share an XCD's L2.
// 1024 thr (16 waves, 4x4 wave grid, 64x64 tile -> acc 64 VGPR).
// bf16 reg-staged single-buffer LDS (32KB), XOR-swizzled, 1-chunk prefetch.
// Epilogue: atomicAdd into G/Gkk (67MB total; no partials, no kbf).
// ---------------------------------------------------------------------------
__global__ __launch_bounds__(1024, 4) void gram_k(
    const float* __restrict__ qg, const float* __restrict__ kg,
    float* __restrict__ Gd, float* __restrict__ Gkkd,
    float* __restrict__ sq, float* __restrict__ sk) {
  __shared__ __align__(16) __bf16 lA[256 * 32];
  __shared__ __align__(16) __bf16 lB[256 * 32];

  // --- XCD-aware (b, s) remap (bijective; dispatch round-robins bid%8) ---
  const int bid = blockIdx.x;
  const int x = bid & 7;
  int n = bid >> 3;  // 0..31: n-th wg on XCD x
  int b = 0, s = 0;
  for (int bb = 0; bb < 8; ++bb) {
    const int gsl = (x - bb) & 7;
    const int gs = (21 * gsl + 7) >> 3, ge = (21 * gsl + 28) >> 3;
    const int ks = (11 * gsl + 7) >> 3, ke = (11 * gsl + 18) >> 3;
    const int cnt = (ge - gs) + (ke - ks);
    if (n < cnt) {
      b = bb;
      s = (n < ge - gs) ? (gs + n) : (21 + ks + (n - (ge - gs)));
      break;
    }
    n -= cnt;
  }

  const int mat = (s < 21) ? 0 : 1;
  const int idx = mat ? (s - 21) : s;
  const int parts = mat ? 11 : 21;
  const int c0 = (800 * idx) / parts, c1 = (800 * (idx + 1)) / parts;
  const int nc = c1 - c0;
  const int tid = threadIdx.x;
  const int w = tid >> 6, lane = tid & 63;
  const int wr = w >> 2, wc = w & 3;
  const int lr = lane & 15, g = lane >> 4;
  const float* Ag = (mat ? kg : qg) + (size_t)b * NCH * LROW;
  const float* Bg = kg + (size_t)b * NCH * LROW;

  // staging: thread owns (row = tid>>2, 8-float unit u = tid&3)
  const int rowS = tid >> 2, uS = tid & 3;
  const int uSw = uS ^ ((rowS >> 1) & 3);
  const size_t gOff = (size_t)rowS * LROW + uS * 8;
  __bf16* ldsA_dst = lA + rowS * 32 + uSw * 8;
  __bf16* ldsB_dst = lB + rowS * 32 + uSw * 8;

  const f32x4 zero = {0.f, 0.f, 0.f, 0.f};
  f32x4 acc[4][4];
#pragma unroll
  for (int i = 0; i < 4; ++i)
#pragma unroll
    for (int j = 0; j < 4; ++j) acc[i][j] = zero;

  float rsum = 0.f;

  auto LOADG = [&](int c, f32x4* d) {
    const float* pa = Ag + gOff + (size_t)c * 32;
    d[0] = *(const f32x4*)pa;
    d[1] = *(const f32x4*)(pa + 4);
    if (mat == 0) {
      const float* pb = Bg + gOff + (size_t)c * 32;
      d[2] = *(const f32x4*)pb;
      d[3] = *(const f32x4*)(pb + 4);
    }
  };

  auto PROCESS = [&](f32x4* d) {
#pragma unroll
    for (int e = 0; e < 4; ++e) rsum += d[0][e] + d[1][e];
    *(bf16x8*)ldsA_dst = cvt8(d[0], d[1]);
    if (mat == 0) *(bf16x8*)ldsB_dst = cvt8(d[2], d[3]);
    wg_bar();
    const __bf16* Bp = mat ? lA : lB;
    bf16x8 af[4];
#pragma unroll
    for (int i = 0; i < 4; ++i) {
      const int row = wr * 64 + i * 16 + lr;
      const int u = g ^ ((row >> 1) & 3);
      af[i] = *(const bf16x8*)(lA + row * 32 + u * 8);
    }
#pragma unroll
    for (int j = 0; j < 4; ++j) {
      const int row = wc * 64 + j * 16 + lr;
      const int u = g ^ ((row >> 1) & 3);
      bf16x8 bfj = *(const bf16x8*)(Bp + row * 32 + u * 8);
#pragma unroll
      for (int i = 0; i < 4; ++i)
        acc[i][j] = __builtin_amdgcn_mfma_f32_16x16x32_bf16(af[i], bfj, acc[i][j], 0, 0, 0);
    }
    wg_bar();
  };

  f32x4 bA[4], bB[4];
  LOADG(c0, bA);
  int cc = 0;
  for (; cc + 2 <= nc; cc += 2) {
    LOADG(c0 + cc + 1, bB);
    PROCESS(bA);
    if (cc + 2 < nc) LOADG(c0 + cc + 2, bA);
    PROCESS(bB);
  }
  if (cc < nc) PROCESS(bA);

  // row sums: G-wgs sum q -> sq, Gkk-wgs sum k -> sk (exact fp32)
  atomicAdd((mat ? sk : sq) + b * NCH + rowS, rsum);

  float* Gout = (mat ? Gkkd : Gd) + (size_t)b * 65536;
#pragma unroll
  for (int i = 0; i < 4; ++i)
#pragma unroll
    for (int j = 0; j < 4; ++j) {
      const int col = wc * 64 + j * 16 + lr;
      const int row0 = wr * 64 + i * 16 + g * 4;
#pragma unroll
      for (int r = 0; r < 4; ++r)
        atomicAdd(&Gout[(size_t)(row0 + r) * NCH + col], acc[i][j][r]);
    }
}

// ---------------------------------------------------------------------------
// Kernel B1: per (batch, head): scores -> softmax -> M = A*Wv_h, cvec = A*bv_h
// ---------------------------------------------------------------------------
__global__ __launch_bounds__(256) void attn_k(
    const float* __restrict__ G, const float* __restrict__ sq,
    const float* __restrict__ sk,
    const float* __restrict__ Wq, const float* __restrict__ bq,
    const float* __restrict__ Wk, const float* __restrict__ bk,
    const float* __restrict__ Wv, const float* __restrict__ bv,
    float* __restrict__ M, float* __restrict__ cvec) {
  __shared__ float Wql[32][257];
  __shared__ float Wkl[32][257];
  __shared__ float QGl[32][257];
  __shared__ float Sl[32][33];
  __shared__ float Al[32][33];
  __shared__ float ul[32], wl[32];
  const int b = blockIdx.x >> 3, h = blockIdx.x & 7;
  const int t = threadIdx.x;
  const float* Gb = G + (size_t)b * 65536;

  for (int i = 0; i < 32; ++i) {
    int idx = i * 256 + t;
    int d = idx >> 8, c = idx & 255;
    Wql[d][c] = Wq[(h * 32 + d) * 256 + c];
    Wkl[d][c] = Wk[(h * 32 + d) * 256 + c];
  }
  __syncthreads();
  {
    float a[32];
#pragma unroll
    for (int d = 0; d < 32; ++d) a[d] = 0.f;
    for (int c = 0; c < 256; ++c) {
      float gv = Gb[c * 256 + t];
#pragma unroll
      for (int d = 0; d < 32; ++d) a[d] += Wql[d][c] * gv;
    }
    for (int d = 0; d < 32; ++d) QGl[d][t] = a[d];
  }
  if (t < 32) {
    float u = 0.f, wv = 0.f;
    for (int c = 0; c < 256; ++c) {
      u += Wql[t][c] * sq[b * 256 + c];
      wv += Wkl[t][c] * sk[b * 256 + c];
    }
    ul[t] = u; wl[t] = wv;
  }
  __syncthreads();
  for (int i = 0; i < 4; ++i) {
    int idx = i * 256 + t;
    int d = idx >> 5, e = idx & 31;
    float sv = 0.f;
    for (int c = 0; c < 256; ++c) sv += QGl[d][c] * Wkl[e][c];
    float bqd = bq[h * 32 + d], bke = bk[h * 32 + e];
    Sl[d][e] = (sv + ul[d] * bke + bqd * wl[e] + 25600.f * bqd * bke) * (1.f / 16.f);
  }
  __syncthreads();
  if (t < 32) {
    float m = -1e30f;
    for (int e = 0; e < 32; ++e) m = fmaxf(m, Sl[t][e]);
    float ssum = 0.f;
    for (int e = 0; e < 32; ++e) { float p = __expf(Sl[t][e] - m); Al[t][e] = p; ssum += p; }
    float is = 1.f / ssum;
    for (int e = 0; e < 32; ++e) Al[t][e] *= is;
  }
  __syncthreads();
  {
    float a[32];
#pragma unroll
    for (int d = 0; d < 32; ++d) a[d] = 0.f;
    for (int e = 0; e < 32; ++e) {
      float wv = Wv[(h * 32 + e) * 256 + t];
#pragma unroll
      for (int d = 0; d < 32; ++d) a[d] += Al[d][e] * wv;
    }
    for (int d = 0; d < 32; ++d) M[((size_t)b * 256 + h * 32 + d) * 256 + t] = a[d];
  }
  if (t < 32) {
    float cv = 0.f;
    for (int e = 0; e < 32; ++e) cv += Al[t][e] * bv[h * 32 + e];
    cvec[b * 256 + h * 32 + t] = cv;
  }
}

// ---------------------------------------------------------------------------
// Kernel B2: LN stats via quadratic form  qf[c] = M[c,:] Gkk M[c,:]^T
// ---------------------------------------------------------------------------
__global__ __launch_bounds__(256) void stats_k(
    const float* __restrict__ Gkk, const float* __restrict__ M,
    const float* __restrict__ sk, const float* __restrict__ cvec,
    float* __restrict__ mu, float* __restrict__ inv) {
  __shared__ float Ml[32][257];
  __shared__ float Ql[32][257];
  const int b = blockIdx.x >> 3, cb = blockIdx.x & 7;
  const int t = threadIdx.x;
  const float* Gk = Gkk + (size_t)b * 65536;
  for (int i = 0; i < 32; ++i) {
    int idx = i * 256 + t;
    Ml[idx >> 8][idx & 255] = M[((size_t)b * 256 + cb * 32 + (idx >> 8)) * 256 + (idx & 255)];
  }
  __syncthreads();
  {
    float a[32];
#pragma unroll
    for (int c = 0; c < 32; ++c) a[c] = 0.f;
    for (int cc = 0; cc < 256; ++cc) {
      float gv = Gk[cc * 256 + t];
#pragma unroll
      for (int c = 0; c < 32; ++c) a[c] += Ml[c][cc] * gv;
    }
    for (int c = 0; c < 32; ++c) Ql[c][t] = a[c];
  }
  __syncthreads();
  if (t < 32) {
    float qf = 0.f, msk = 0.f;
    for (int j = 0; j < 256; ++j) {
      qf += Ql[t][j] * Ml[t][j];
      msk += Ml[t][j] * sk[b * 256 + j];
    }
    int c = cb * 32 + t;
    float cv = cvec[b * 256 + c];
    float muv = msk * (1.f / 25600.f) + cv;
    float sum2 = qf + 2.f * cv * msk + 25600.f * cv * cv;
    float var = sum2 * (1.f / 25600.f) - muv * muv;
    mu[b * 256 + c] = muv;
    inv[b * 256 + c] = rsqrtf(var + LN_EPS);
  }
}

// ---------------------------------------------------------------------------
// Kernel B3: P = (Wo o inv) M  (bf16), t1, wsum
// ---------------------------------------------------------------------------
__global__ __launch_bounds__(256) void pmat_k(
    const float* __restrict__ M, const float* __restrict__ Wo,
    const float* __restrict__ inv, const float* __restrict__ cvec,
    const float* __restrict__ mu, __bf16* __restrict__ Pb,
    float* __restrict__ t1, float* __restrict__ wsum) {
  __shared__ float Wol[32][257];
  __shared__ float invl[256];
  const int b = blockIdx.x >> 3, ob = blockIdx.x & 7;
  const int t = threadIdx.x;
  invl[t] = inv[b * 256 + t];
  __syncthreads();
  for (int i = 0; i < 32; ++i) {
    int idx = i * 256 + t;
    int o = idx >> 8, c = idx & 255;
    Wol[o][c] = Wo[(ob * 32 + o) * 256 + c] * invl[c];
  }
  __syncthreads();
  {
    float a[32];
#pragma unroll
    for (int o = 0; o < 32; ++o) a[o] = 0.f;
    for (int c = 0; c < 256; ++c) {
      float m = M[((size_t)b * 256 + c) * 256 + t];
#pragma unroll
      for (int o = 0; o < 32; ++o) a[o] += Wol[o][c] * m;
    }
    for (int o = 0; o < 32; ++o)
      Pb[((size_t)b * 256 + ob * 32 + o) * 256 + t] = (__bf16)a[o];
  }
  if (t < 32) {
    float s1 = 0.f, s2 = 0.f;
    for (int c = 0; c < 256; ++c) {
      s1 += Wol[t][c] * (cvec[b * 256 + c] - mu[b * 256 + c]);
      s2 += Wo[(ob * 32 + t) * 256 + c];
    }
    t1[b * 256 + ob * 32 + t] = s1;
    wsum[b * 256 + ob * 32 + t] = s2;
  }
}

// ---------------------------------------------------------------------------
// Kernel C v3: out = gamma*(P key + t1) + beta*wsum + bo  (fused LN + conv).
// 1600 wgs (b x 128-l tile), 512 thr, 8 waves (4r x 2c), 64KB LDS, 2 wg/CU.
// key staged from fp32 with f32x4 loads (contiguous per lane), transposed
// into XOR-swizzled bf16 Bt[l][c] via conflict-free b16 writes.
// ---------------------------------------------------------------------------
__global__ __launch_bounds__(512, 4) void outf_k(
    const float* __restrict__ key, const __bf16* __restrict__ Pb,
    const float* __restrict__ t1, const float* __restrict__ wsum,
    const float* __restrict__ bo, const float* __restrict__ gamma,
    const float* __restrict__ beta, float* __restrict__ out) {
  __shared__ __align__(16) __bf16 Bt[128 * 256];  // [l][c], XOR-swizzled, 64KB
  const int bid = blockIdx.x;
  const int b = bid / 200, lt = bid % 200, l0 = lt * 128;
  const int tid = threadIdx.x, w = tid >> 6, lane = tid & 63;
  const int wr = w >> 1, wc = w & 1;
  const int lr = lane & 15, g = lane >> 4;
  const float* Kb = key + (size_t)b * NCH * LROW;

  // stage: thread = (channel c, l-half seg); 16x f32x4 contiguous per lane
  {
    const int c = tid & 255, seg = tid >> 8;
    const int uc = c >> 3, cb2 = (c & 7) * 2;
    const float* src = Kb + (size_t)c * LROW + l0 + seg * 64;
#pragma unroll
    for (int i = 0; i < 16; ++i) {
      f32x4 v = *(const f32x4*)(src + i * 4);
#pragma unroll
      for (int j = 0; j < 4; ++j) {
        const int l = seg * 64 + i * 4 + j;
        *(__bf16*)((char*)Bt + l * 512 + ((uc ^ (l & 7)) << 4) + cb2) = (__bf16)v[j];
      }
    }
  }
  __syncthreads();

  const f32x4 zero = {0.f, 0.f, 0.f, 0.f};
  f32x4 acc[4][4];
#pragma unroll
  for (int i = 0; i < 4; ++i)
#pragma unroll
    for (int j = 0; j < 4; ++j) acc[i][j] = zero;

  const __bf16* Pbase = Pb + (size_t)b * 65536;
#pragma unroll
  for (int ks = 0; ks < 8; ++ks) {
    bf16x8 af[4];
#pragma unroll
    for (int i = 0; i < 4; ++i) {
      const int row = wr * 64 + i * 16 + lr;
      af[i] = *(const bf16x8*)(Pbase + (size_t)row * 256 + ks * 32 + g * 8);
    }
#pragma unroll
    for (int j = 0; j < 4; ++j) {
      const int col = wc * 64 + j * 16 + lr;
      const int unit = ks * 4 + g;
      bf16x8 bfj = *(const bf16x8*)((const char*)Bt + col * 512 + ((unit ^ (col & 7)) << 4));
#pragma unroll
      for (int i = 0; i < 4; ++i)
        acc[i][j] = __builtin_amdgcn_mfma_f32_16x16x32_bf16(af[i], bfj, acc[i][j], 0, 0, 0);
    }
  }

  float t1r[4][4], wsr[4][4], bor[4][4];
#pragma unroll
  for (int i = 0; i < 4; ++i)
#pragma unroll
    for (int r = 0; r < 4; ++r) {
      const int row = wr * 64 + i * 16 + g * 4 + r;
      t1r[i][r] = t1[b * 256 + row];
      wsr[i][r] = wsum[b * 256 + row];
      bor[i][r] = bo[row];
    }
#pragma unroll
  for (int j = 0; j < 4; ++j) {
    const int colg = l0 + wc * 64 + j * 16 + lr;
    const float gm = gamma[colg];
    const float bt = beta[colg];
#pragma unroll
    for (int i = 0; i < 4; ++i) {
      const int row0 = wr * 64 + i * 16 + g * 4;
#pragma unroll
      for (int r = 0; r < 4; ++r) {
        const int row = row0 + r;
        float v = gm * (acc[i][j][r] + t1r[i][r]) + bt * wsr[i][r] + bor[i][r];
        out[((size_t)b * 256 + row) * LROW + colg] = v;
      }
    }
  }
}

// ---------------------------------------------------------------------------
extern "C" void kernel_launch(void* const* d_in, const int* in_sizes, int n_in,
                              void* d_out, int out_size, void* d_ws, size_t ws_size,
                              hipStream_t stream) {
  const float* query = (const float*)d_in[0];
  const float* key   = (const float*)d_in[1];
  const float* Wq = (const float*)d_in[2];
  const float* bq = (const float*)d_in[3];
  const float* Wk = (const float*)d_in[4];
  const float* bk = (const float*)d_in[5];
  const float* Wv = (const float*)d_in[6];
  const float* bv = (const float*)d_in[7];
  const float* Wo = (const float*)d_in[8];
  const float* bo = (const float*)d_in[9];
  const float* gamma = (const float*)d_in[10];
  const float* beta  = (const float*)d_in[11];
  float* out = (float*)d_out;

  float* ws = (float*)d_ws;
  float* G    = ws;                  // 524288
  float* Gkk  = G + 524288;          // 524288
  float* sq   = Gkk + 524288;        // 2048
  float* sk   = sq + 2048;           // 2048
  float* M    = sk + 2048;           // 524288
  float* cvec = M + 524288;          // 2048
  float* mu   = cvec + 2048;         // 2048
  float* inv  = mu + 2048;           // 2048
  float* t1   = inv + 2048;          // 2048
  float* wsum = t1 + 2048;           // 2048
  __bf16* Pb  = (__bf16*)(wsum + 2048);  // 524288 bf16

  // zero atomic-accumulated buffers (G, Gkk, sq, sk)
  hipMemsetAsync(d_ws, 0, (size_t)(524288 * 2 + 4096) * sizeof(float), stream);

  gram_k<<<256, 1024, 0, stream>>>(query, key, G, Gkk, sq, sk);
  attn_k<<<64, 256, 0, stream>>>(G, sq, sk, Wq, bq, Wk, bk, Wv, bv, M, cvec);
  stats_k<<<64, 256, 0, stream>>>(Gkk, M, sk, cvec, mu, inv);
  pmat_k<<<64, 256, 0, stream>>>(M, Wo, inv, cvec, mu, Pb, t1, wsum);
  outf_k<<<1600, 512, 0, stream>>>(key, Pb, t1, wsum, bo, gamma, beta, out);
}